// Round 2
// baseline (2887.119 us; speedup 1.0000x reference)
//
#include <hip/hip_runtime.h>

#define D_MODEL 1024
#define NUM_HEADS 16
#define HEAD_DIM 64
#define BATCH 2
#define SEQ 2048
#define MTOT (BATCH * SEQ)   // 4096 rows

// ---------------------------------------------------------------------------
// GEMM: out = A[M,K] @ W[N,K]^T   (nn.Linear convention, both row-major)
// 64x64 tile, 256 threads, 4x4 micro-tile, K-transposed LDS for b128 reads.
// ---------------------------------------------------------------------------

// QKV projection: computes x @ W{q,k,v}^T and scatters into [b,h,s,d] layout.
__global__ __launch_bounds__(256)
void qkv_gemm_kernel(const float* __restrict__ x,
                     const float* __restrict__ Wq,
                     const float* __restrict__ Wk,
                     const float* __restrict__ Wv,
                     float* __restrict__ Qo,
                     float* __restrict__ Ko,
                     float* __restrict__ Vo)
{
    const int z = blockIdx.z;
    const float* __restrict__ W = (z == 0) ? Wq : (z == 1) ? Wk : Wv;
    float* __restrict__ outp    = (z == 0) ? Qo : (z == 1) ? Ko : Vo;

    __shared__ float As[16][68];   // [k][m], stride 68 keeps float4 16B-aligned
    __shared__ float Bs[16][68];   // [k][n]

    const int tid = threadIdx.x;
    const int tx = tid & 15;
    const int ty = tid >> 4;
    const int m0 = blockIdx.y * 64;
    const int n0 = blockIdx.x * 64;

    const int lrow = tid >> 2;          // 0..63
    const int lk4  = (tid & 3) << 2;    // 0,4,8,12

    float acc[4][4] = {};

    for (int k0 = 0; k0 < D_MODEL; k0 += 16) {
        const float4 av = *reinterpret_cast<const float4*>(
            &x[(size_t)(m0 + lrow) * D_MODEL + k0 + lk4]);
        const float4 bv = *reinterpret_cast<const float4*>(
            &W[(size_t)(n0 + lrow) * D_MODEL + k0 + lk4]);
        As[lk4 + 0][lrow] = av.x; As[lk4 + 1][lrow] = av.y;
        As[lk4 + 2][lrow] = av.z; As[lk4 + 3][lrow] = av.w;
        Bs[lk4 + 0][lrow] = bv.x; Bs[lk4 + 1][lrow] = bv.y;
        Bs[lk4 + 2][lrow] = bv.z; Bs[lk4 + 3][lrow] = bv.w;
        __syncthreads();

        #pragma unroll
        for (int kk = 0; kk < 16; ++kk) {
            const float4 a4 = *reinterpret_cast<const float4*>(&As[kk][ty * 4]);
            const float4 b4 = *reinterpret_cast<const float4*>(&Bs[kk][tx * 4]);
            const float aa[4] = {a4.x, a4.y, a4.z, a4.w};
            const float bb[4] = {b4.x, b4.y, b4.z, b4.w};
            #pragma unroll
            for (int i = 0; i < 4; ++i)
                #pragma unroll
                for (int j = 0; j < 4; ++j)
                    acc[i][j] = __builtin_fmaf(aa[i], bb[j], acc[i][j]);
        }
        __syncthreads();
    }

    #pragma unroll
    for (int i = 0; i < 4; ++i) {
        const int m = m0 + ty * 4 + i;
        const int b = m >> 11;             // m / SEQ
        const int s = m & (SEQ - 1);
        #pragma unroll
        for (int j = 0; j < 4; ++j) {
            const int c = n0 + tx * 4 + j;
            const int h = c >> 6;
            const int d = c & 63;
            outp[((size_t)((b * NUM_HEADS + h) * SEQ + s)) * HEAD_DIM + d] = acc[i][j];
        }
    }
}

// Output projection: out = ctx @ Wo^T + bo   (plain [m,n] output)
__global__ __launch_bounds__(256)
void out_gemm_kernel(const float* __restrict__ A,
                     const float* __restrict__ W,
                     const float* __restrict__ bias,
                     float* __restrict__ out)
{
    __shared__ float As[16][68];
    __shared__ float Bs[16][68];

    const int tid = threadIdx.x;
    const int tx = tid & 15;
    const int ty = tid >> 4;
    const int m0 = blockIdx.y * 64;
    const int n0 = blockIdx.x * 64;

    const int lrow = tid >> 2;
    const int lk4  = (tid & 3) << 2;

    float acc[4][4] = {};

    for (int k0 = 0; k0 < D_MODEL; k0 += 16) {
        const float4 av = *reinterpret_cast<const float4*>(
            &A[(size_t)(m0 + lrow) * D_MODEL + k0 + lk4]);
        const float4 bv = *reinterpret_cast<const float4*>(
            &W[(size_t)(n0 + lrow) * D_MODEL + k0 + lk4]);
        As[lk4 + 0][lrow] = av.x; As[lk4 + 1][lrow] = av.y;
        As[lk4 + 2][lrow] = av.z; As[lk4 + 3][lrow] = av.w;
        Bs[lk4 + 0][lrow] = bv.x; Bs[lk4 + 1][lrow] = bv.y;
        Bs[lk4 + 2][lrow] = bv.z; Bs[lk4 + 3][lrow] = bv.w;
        __syncthreads();

        #pragma unroll
        for (int kk = 0; kk < 16; ++kk) {
            const float4 a4 = *reinterpret_cast<const float4*>(&As[kk][ty * 4]);
            const float4 b4 = *reinterpret_cast<const float4*>(&Bs[kk][tx * 4]);
            const float aa[4] = {a4.x, a4.y, a4.z, a4.w};
            const float bb[4] = {b4.x, b4.y, b4.z, b4.w};
            #pragma unroll
            for (int i = 0; i < 4; ++i)
                #pragma unroll
                for (int j = 0; j < 4; ++j)
                    acc[i][j] = __builtin_fmaf(aa[i], bb[j], acc[i][j]);
        }
        __syncthreads();
    }

    #pragma unroll
    for (int i = 0; i < 4; ++i) {
        const int m = m0 + ty * 4 + i;
        #pragma unroll
        for (int j = 0; j < 4; ++j) {
            const int c = n0 + tx * 4 + j;
            out[(size_t)m * D_MODEL + c] = acc[i][j] + bias[c];
        }
    }
}

// ---------------------------------------------------------------------------
// Causal flash attention, fp32. One thread = one query row (64 queries/block,
// 1 wave). K/V tiles 64x64 staged in LDS; inner-loop LDS reads are wave-
// broadcast (same key row across lanes) -> conflict-free.
// ---------------------------------------------------------------------------
__global__ __launch_bounds__(64)
void attn_kernel(const float* __restrict__ Q,
                 const float* __restrict__ K,
                 const float* __restrict__ V,
                 float* __restrict__ ctx)
{
    const int qt  = blockIdx.x;          // query tile (64 rows)
    const int bh  = blockIdx.y;          // b*NUM_HEADS + h
    const int tid = threadIdx.x;         // 0..63
    const int qidx = qt * 64 + tid;      // query row in sequence

    const float* __restrict__ Qh = Q + (size_t)bh * SEQ * HEAD_DIM;
    const float* __restrict__ Kh = K + (size_t)bh * SEQ * HEAD_DIM;
    const float* __restrict__ Vh = V + (size_t)bh * SEQ * HEAD_DIM;

    float q[HEAD_DIM];
    #pragma unroll
    for (int d = 0; d < HEAD_DIM; d += 4) {
        const float4 t = *reinterpret_cast<const float4*>(&Qh[(size_t)qidx * HEAD_DIM + d]);
        q[d + 0] = t.x * 0.125f;   // 1/sqrt(HEAD_DIM) folded into q
        q[d + 1] = t.y * 0.125f;
        q[d + 2] = t.z * 0.125f;
        q[d + 3] = t.w * 0.125f;
    }

    float o[HEAD_DIM] = {};
    float mrun = -3.0e38f;
    float lrun = 0.0f;

    __shared__ float Ks[64][HEAD_DIM];
    __shared__ float Vs[64][HEAD_DIM];

    for (int kt = 0; kt <= qt; ++kt) {
        __syncthreads();   // protect previous iteration's LDS reads
        #pragma unroll
        for (int i = 0; i < 16; ++i) {
            const int row = i * 4 + (tid >> 4);
            const int c4  = (tid & 15) << 2;
            *reinterpret_cast<float4*>(&Ks[row][c4]) =
                *reinterpret_cast<const float4*>(&Kh[((size_t)(kt * 64 + row)) * HEAD_DIM + c4]);
            *reinterpret_cast<float4*>(&Vs[row][c4]) =
                *reinterpret_cast<const float4*>(&Vh[((size_t)(kt * 64 + row)) * HEAD_DIM + c4]);
        }
        __syncthreads();

        const int nk = min(64, qidx - kt * 64 + 1);   // causal key count in tile
        for (int j = 0; j < nk; ++j) {
            float s0 = 0.f, s1 = 0.f, s2 = 0.f, s3 = 0.f;
            #pragma unroll
            for (int d = 0; d < HEAD_DIM; d += 4) {
                s0 = __builtin_fmaf(q[d + 0], Ks[j][d + 0], s0);
                s1 = __builtin_fmaf(q[d + 1], Ks[j][d + 1], s1);
                s2 = __builtin_fmaf(q[d + 2], Ks[j][d + 2], s2);
                s3 = __builtin_fmaf(q[d + 3], Ks[j][d + 3], s3);
            }
            const float sc = (s0 + s1) + (s2 + s3);
            const float mn   = fmaxf(mrun, sc);
            const float corr = __expf(mrun - mn);
            const float p    = __expf(sc - mn);
            lrun = lrun * corr + p;
            #pragma unroll
            for (int d = 0; d < HEAD_DIM; ++d)
                o[d] = __builtin_fmaf(o[d], corr, p * Vs[j][d]);
            mrun = mn;
        }
    }

    const float inv = 1.0f / lrun;
    const int b = bh >> 4;
    const int h = bh & (NUM_HEADS - 1);
    float* __restrict__ orow =
        ctx + ((size_t)(b * SEQ + qidx)) * D_MODEL + h * HEAD_DIM;
    #pragma unroll
    for (int d = 0; d < HEAD_DIM; d += 4) {
        float4 t;
        t.x = o[d + 0] * inv; t.y = o[d + 1] * inv;
        t.z = o[d + 2] * inv; t.w = o[d + 3] * inv;
        *reinterpret_cast<float4*>(&orow[d]) = t;
    }
}

// ---------------------------------------------------------------------------

extern "C" void kernel_launch(void* const* d_in, const int* in_sizes, int n_in,
                              void* d_out, int out_size, void* d_ws, size_t ws_size,
                              hipStream_t stream)
{
    const float* x  = (const float*)d_in[0];
    const float* Wq = (const float*)d_in[1];
    const float* Wk = (const float*)d_in[2];
    const float* Wv = (const float*)d_in[3];
    const float* Wo = (const float*)d_in[4];
    const float* bo = (const float*)d_in[5];
    float* out = (float*)d_out;

    // Workspace layout: Q, K, V in [b,h,s,d], ctx in [b,s,h*d]. 64 MB total.
    float* Qw = (float*)d_ws;
    float* Kw = Qw + (size_t)MTOT * D_MODEL;
    float* Vw = Kw + (size_t)MTOT * D_MODEL;
    float* Cw = Vw + (size_t)MTOT * D_MODEL;

    dim3 gq(D_MODEL / 64, MTOT / 64, 3);
    qkv_gemm_kernel<<<gq, 256, 0, stream>>>(x, Wq, Wk, Wv, Qw, Kw, Vw);

    dim3 ga(SEQ / 64, BATCH * NUM_HEADS);
    attn_kernel<<<ga, 64, 0, stream>>>(Qw, Kw, Vw, Cw);

    dim3 go(D_MODEL / 64, MTOT / 64);
    out_gemm_kernel<<<go, 256, 0, stream>>>(Cw, Wo, bo, out);
}

// Round 3
// 210.960 us; speedup vs baseline: 13.6856x; 13.6856x over previous
//
#include <hip/hip_runtime.h>

#define D_MODEL 1024
#define NUM_HEADS 16
#define HEAD_DIM 64
#define BATCH 2
#define SEQ 2048
#define MTOT (BATCH * SEQ)   // 4096

typedef __attribute__((ext_vector_type(8))) short bf16x8;   // 8 bf16 in 4 VGPRs
typedef __attribute__((ext_vector_type(4))) float f32x4;
typedef unsigned short u16;

__device__ __forceinline__ u16 f2bf(float f) {
    unsigned u = __float_as_uint(f);
    return (u16)((u + 0x7FFFu + ((u >> 16) & 1u)) >> 16);   // RNE, finite data
}

#define GLOAD16(gp, lp) __builtin_amdgcn_global_load_lds(                      \
    (const __attribute__((address_space(1))) void*)(gp),                       \
    (__attribute__((address_space(3))) void*)(lp), 16, 0, 0)

// ---------------------------------------------------------------------------
// fp32 -> bf16 casts
// ---------------------------------------------------------------------------
__global__ __launch_bounds__(256)
void cast_kernel(const float* __restrict__ src, u16* __restrict__ dst, int n8)
{
    int i = blockIdx.x * 256 + threadIdx.x;
    if (i >= n8) return;
    const float4* s = reinterpret_cast<const float4*>(src) + (size_t)i * 2;
    float4 a = s[0], b = s[1];
    u16 tmp[8] = {f2bf(a.x), f2bf(a.y), f2bf(a.z), f2bf(a.w),
                  f2bf(b.x), f2bf(b.y), f2bf(b.z), f2bf(b.w)};
    *reinterpret_cast<int4*>(dst + (size_t)i * 8) = *reinterpret_cast<int4*>(tmp);
}

// Wq,Wk,Wv -> one contiguous bf16 [3072][1024]
__global__ __launch_bounds__(256)
void cast_qkv_kernel(const float* __restrict__ Wq, const float* __restrict__ Wk,
                     const float* __restrict__ Wv, u16* __restrict__ dst)
{
    int i = blockIdx.x * 256 + threadIdx.x;           // 393216 groups of 8
    int z = i >> 17;                                  // 131072 groups per matrix
    int j = i & 0x1FFFF;
    const float* src = (z == 0) ? Wq : (z == 1) ? Wk : Wv;
    const float4* s = reinterpret_cast<const float4*>(src) + (size_t)j * 2;
    float4 a = s[0], b = s[1];
    u16 tmp[8] = {f2bf(a.x), f2bf(a.y), f2bf(a.z), f2bf(a.w),
                  f2bf(b.x), f2bf(b.y), f2bf(b.z), f2bf(b.w)};
    *reinterpret_cast<int4*>(dst + (size_t)i * 8) = *reinterpret_cast<int4*>(tmp);
}

// ---------------------------------------------------------------------------
// QKV GEMM: xb[4096][1024] @ Wqkv[3072][1024]^T, bf16 MFMA, m97 structure.
// Epilogue scatters Q,K to [b,h,s,d] and V transposed to [b,h,d,s].
// ---------------------------------------------------------------------------
__global__ __launch_bounds__(256)
void gemm_qkv_kernel(const u16* __restrict__ A, const u16* __restrict__ B,
                     u16* __restrict__ Qo, u16* __restrict__ Ko, u16* __restrict__ Vt)
{
    __shared__ u16 Al[128 * 64];
    __shared__ u16 Bl[128 * 64];

    const int tid = threadIdx.x;
    const int l = tid & 63;
    const int w = tid >> 6;
    const int wm = w >> 1, wn = w & 1;
    const int lr = l & 15, lg = l >> 4;
    const int m0 = blockIdx.y * 128;
    const int n0 = blockIdx.x * 128;

    const int srow = tid >> 3;          // 0..31
    const int scol = (tid & 7) * 8;     // element col

    f32x4 acc[4][4];
    #pragma unroll
    for (int i = 0; i < 4; ++i)
        #pragma unroll
        for (int j = 0; j < 4; ++j) acc[i][j] = (f32x4){0.f, 0.f, 0.f, 0.f};

    for (int k0 = 0; k0 < D_MODEL; k0 += 64) {
        __syncthreads();
        #pragma unroll
        for (int i = 0; i < 4; ++i) {
            const u16* ga = A + (size_t)(m0 + i * 32 + srow) * D_MODEL + k0 + scol;
            const u16* gb = B + (size_t)(n0 + i * 32 + srow) * D_MODEL + k0 + scol;
            GLOAD16(ga, Al + i * 2048 + w * 512);
            GLOAD16(gb, Bl + i * 2048 + w * 512);
        }
        __syncthreads();
        #pragma unroll
        for (int kc = 0; kc < 2; ++kc) {
            bf16x8 af[4], bfr[4];
            #pragma unroll
            for (int i = 0; i < 4; ++i)
                af[i] = *reinterpret_cast<const bf16x8*>(
                    &Al[(wm * 64 + i * 16 + lr) * 64 + kc * 32 + lg * 8]);
            #pragma unroll
            for (int j = 0; j < 4; ++j)
                bfr[j] = *reinterpret_cast<const bf16x8*>(
                    &Bl[(wn * 64 + j * 16 + lr) * 64 + kc * 32 + lg * 8]);
            #pragma unroll
            for (int i = 0; i < 4; ++i)
                #pragma unroll
                for (int j = 0; j < 4; ++j)
                    acc[i][j] = __builtin_amdgcn_mfma_f32_16x16x32_bf16(
                        af[i], bfr[j], acc[i][j], 0, 0, 0);
        }
    }

    const int z = (n0 >> 10);           // 0=Q 1=K 2=V (uniform per block)
    #pragma unroll
    for (int i = 0; i < 4; ++i) {
        #pragma unroll
        for (int r = 0; r < 4; ++r) {
            const int m = m0 + wm * 64 + i * 16 + lg * 4 + r;
            const int bb = m >> 11, s = m & (SEQ - 1);
            #pragma unroll
            for (int j = 0; j < 4; ++j) {
                const int c = n0 + wn * 64 + j * 16 + lr;
                const int cc = c & 1023, h = cc >> 6, d = cc & 63;
                const u16 val = f2bf(acc[i][j][r]);
                if (z == 0)
                    Qo[((size_t)(bb * NUM_HEADS + h) * SEQ + s) * 64 + d] = val;
                else if (z == 1)
                    Ko[((size_t)(bb * NUM_HEADS + h) * SEQ + s) * 64 + d] = val;
                else
                    Vt[((size_t)(bb * NUM_HEADS + h) * 64 + d) * SEQ + s] = val;
            }
        }
    }
}

// ---------------------------------------------------------------------------
// Output GEMM: ctx[4096][1024] @ Wo[1024][1024]^T + bo, fp32 out.
// ---------------------------------------------------------------------------
__global__ __launch_bounds__(256)
void gemm_out_kernel(const u16* __restrict__ A, const u16* __restrict__ B,
                     const float* __restrict__ bias, float* __restrict__ out)
{
    __shared__ u16 Al[128 * 64];
    __shared__ u16 Bl[128 * 64];

    const int tid = threadIdx.x;
    const int l = tid & 63;
    const int w = tid >> 6;
    const int wm = w >> 1, wn = w & 1;
    const int lr = l & 15, lg = l >> 4;
    const int m0 = blockIdx.y * 128;
    const int n0 = blockIdx.x * 128;

    const int srow = tid >> 3;
    const int scol = (tid & 7) * 8;

    f32x4 acc[4][4];
    #pragma unroll
    for (int i = 0; i < 4; ++i)
        #pragma unroll
        for (int j = 0; j < 4; ++j) acc[i][j] = (f32x4){0.f, 0.f, 0.f, 0.f};

    for (int k0 = 0; k0 < D_MODEL; k0 += 64) {
        __syncthreads();
        #pragma unroll
        for (int i = 0; i < 4; ++i) {
            const u16* ga = A + (size_t)(m0 + i * 32 + srow) * D_MODEL + k0 + scol;
            const u16* gb = B + (size_t)(n0 + i * 32 + srow) * D_MODEL + k0 + scol;
            GLOAD16(ga, Al + i * 2048 + w * 512);
            GLOAD16(gb, Bl + i * 2048 + w * 512);
        }
        __syncthreads();
        #pragma unroll
        for (int kc = 0; kc < 2; ++kc) {
            bf16x8 af[4], bfr[4];
            #pragma unroll
            for (int i = 0; i < 4; ++i)
                af[i] = *reinterpret_cast<const bf16x8*>(
                    &Al[(wm * 64 + i * 16 + lr) * 64 + kc * 32 + lg * 8]);
            #pragma unroll
            for (int j = 0; j < 4; ++j)
                bfr[j] = *reinterpret_cast<const bf16x8*>(
                    &Bl[(wn * 64 + j * 16 + lr) * 64 + kc * 32 + lg * 8]);
            #pragma unroll
            for (int i = 0; i < 4; ++i)
                #pragma unroll
                for (int j = 0; j < 4; ++j)
                    acc[i][j] = __builtin_amdgcn_mfma_f32_16x16x32_bf16(
                        af[i], bfr[j], acc[i][j], 0, 0, 0);
        }
    }

    #pragma unroll
    for (int i = 0; i < 4; ++i) {
        #pragma unroll
        for (int r = 0; r < 4; ++r) {
            const int m = m0 + wm * 64 + i * 16 + lg * 4 + r;
            #pragma unroll
            for (int j = 0; j < 4; ++j) {
                const int c = n0 + wn * 64 + j * 16 + lr;
                out[(size_t)m * D_MODEL + c] = acc[i][j][r] + bias[c];
            }
        }
    }
}

// ---------------------------------------------------------------------------
// MFMA causal flash attention. 4 waves/block, 16 queries/wave, KVBLK=32.
// Q,K in [b,h,s,d]; V transposed [b,h,d,s]. ctx out bf16 [b*s][1024].
// ---------------------------------------------------------------------------
__global__ __launch_bounds__(256)
void attn_kernel(const u16* __restrict__ Q, const u16* __restrict__ K,
                 const u16* __restrict__ Vt, u16* __restrict__ ctx)
{
    __shared__ u16 Ks[32][72];        // [key][d], pad 72 for b128 bank spread
    __shared__ u16 Vs[64][40];        // [d][key], pad 40
    __shared__ float Sw[4][16][36];   // per-wave S transpose buffer

    const int tid = threadIdx.x;
    const int l = tid & 63;
    const int w = tid >> 6;
    const int lr = l & 15;            // row ownership
    const int lg = l >> 4;            // k-group
    const int qtb = blockIdx.x;
    const int bh = blockIdx.y;
    const int q0 = qtb * 64;
    const size_t hbase = (size_t)bh * SEQ * 64;

    // Q fragments (held for whole kernel): rows q0+w*16+lr, d = kc*32+lg*8
    bf16x8 qf[2];
    {
        const u16* qp = Q + hbase + (size_t)(q0 + w * 16 + lr) * 64 + lg * 8;
        qf[0] = *reinterpret_cast<const bf16x8*>(qp);
        qf[1] = *reinterpret_cast<const bf16x8*>(qp + 32);
    }

    f32x4 oacc[4];
    #pragma unroll
    for (int nb = 0; nb < 4; ++nb) oacc[nb] = (f32x4){0.f, 0.f, 0.f, 0.f};
    float mrun = -3.0e38f, lsum = 0.f;

    const int nt = qtb * 2 + 2;       // causal tile count
    for (int kt = 0; kt < nt; ++kt) {
        __syncthreads();
        {   // stage K tile [32][64] and V^T tile [64][32]
            const u16* kg = K + hbase + (size_t)(kt * 32 + (tid >> 3)) * 64 + (tid & 7) * 8;
            *reinterpret_cast<int4*>(&Ks[tid >> 3][(tid & 7) * 8]) =
                *reinterpret_cast<const int4*>(kg);
            const u16* vg = Vt + hbase + (size_t)(tid >> 2) * SEQ + kt * 32 + (tid & 3) * 8;
            *reinterpret_cast<int4*>(&Vs[tid >> 2][(tid & 3) * 8]) =
                *reinterpret_cast<const int4*>(vg);
        }
        __syncthreads();

        // S = Q . K^T  (16 q x 32 keys)
        f32x4 s0 = (f32x4){0.f, 0.f, 0.f, 0.f};
        f32x4 s1 = (f32x4){0.f, 0.f, 0.f, 0.f};
        #pragma unroll
        for (int kc = 0; kc < 2; ++kc) {
            bf16x8 kb0 = *reinterpret_cast<const bf16x8*>(&Ks[lr][kc * 32 + lg * 8]);
            bf16x8 kb1 = *reinterpret_cast<const bf16x8*>(&Ks[16 + lr][kc * 32 + lg * 8]);
            s0 = __builtin_amdgcn_mfma_f32_16x16x32_bf16(qf[kc], kb0, s0, 0, 0, 0);
            s1 = __builtin_amdgcn_mfma_f32_16x16x32_bf16(qf[kc], kb1, s1, 0, 0, 0);
        }
        // transpose S into row-per-lane order via LDS
        #pragma unroll
        for (int r = 0; r < 4; ++r) {
            Sw[w][lg * 4 + r][lr] = s0[r];
            Sw[w][lg * 4 + r][16 + lr] = s1[r];
        }
        __syncthreads();

        float sv[8];
        *reinterpret_cast<float4*>(&sv[0]) =
            *reinterpret_cast<const float4*>(&Sw[w][lr][lg * 8]);
        *reinterpret_cast<float4*>(&sv[4]) =
            *reinterpret_cast<const float4*>(&Sw[w][lr][lg * 8 + 4]);

        const int qrow = q0 + w * 16 + lr;
        float pmax = -3.0e38f;
        #pragma unroll
        for (int j2 = 0; j2 < 8; ++j2) {
            const int kidx = kt * 32 + lg * 8 + j2;
            float s = sv[j2] * 0.125f;               // 1/sqrt(64)
            s = (kidx <= qrow) ? s : -3.0e38f;       // causal mask
            sv[j2] = s;
            pmax = fmaxf(pmax, s);
        }
        pmax = fmaxf(pmax, __shfl_xor(pmax, 16));
        pmax = fmaxf(pmax, __shfl_xor(pmax, 32));
        const float mnew = fmaxf(mrun, pmax);
        const float corr = __expf(mrun - mnew);
        mrun = mnew;

        bf16x8 pa;
        float ps = 0.f;
        #pragma unroll
        for (int j2 = 0; j2 < 8; ++j2) {
            const float p = __expf(sv[j2] - mnew);
            ps += p;
            pa[j2] = (short)f2bf(p);
        }
        ps += __shfl_xor(ps, 16);
        ps += __shfl_xor(ps, 32);
        lsum = lsum * corr + ps;

        // rescale O (rows owned per-lane differ from softmax rows -> shfl)
        #pragma unroll
        for (int r = 0; r < 4; ++r) {
            const float cr = __shfl(corr, (l & 48) | (lg * 4 + r));
            #pragma unroll
            for (int nb = 0; nb < 4; ++nb) oacc[nb][r] *= cr;
        }
        // O += P . V
        #pragma unroll
        for (int nb = 0; nb < 4; ++nb) {
            bf16x8 vb = *reinterpret_cast<const bf16x8*>(&Vs[nb * 16 + lr][lg * 8]);
            oacc[nb] = __builtin_amdgcn_mfma_f32_16x16x32_bf16(pa, vb, oacc[nb], 0, 0, 0);
        }
    }

    const float inv = 1.0f / lsum;
    const int b = bh >> 4, h = bh & (NUM_HEADS - 1);
    #pragma unroll
    for (int r = 0; r < 4; ++r) {
        const float ir = __shfl(inv, (l & 48) | (lg * 4 + r));
        const int row = q0 + w * 16 + lg * 4 + r;
        u16* op = ctx + ((size_t)(b * SEQ) + row) * D_MODEL + h * 64;
        #pragma unroll
        for (int nb = 0; nb < 4; ++nb)
            op[nb * 16 + lr] = f2bf(oacc[nb][r] * ir);
    }
}

// ---------------------------------------------------------------------------

extern "C" void kernel_launch(void* const* d_in, const int* in_sizes, int n_in,
                              void* d_out, int out_size, void* d_ws, size_t ws_size,
                              hipStream_t stream)
{
    const float* x  = (const float*)d_in[0];
    const float* Wq = (const float*)d_in[1];
    const float* Wk = (const float*)d_in[2];
    const float* Wv = (const float*)d_in[3];
    const float* Wo = (const float*)d_in[4];
    const float* bo = (const float*)d_in[5];
    float* out = (float*)d_out;

    // workspace carve (u16 units)
    u16* xb   = (u16*)d_ws;                               // 4096*1024
    u16* wqkv = xb   + (size_t)MTOT * D_MODEL;            // 3072*1024
    u16* wob  = wqkv + (size_t)3 * D_MODEL * D_MODEL;     // 1024*1024
    u16* Qw   = wob  + (size_t)D_MODEL * D_MODEL;         // [b,h,s,d]
    u16* Kw   = Qw   + (size_t)MTOT * D_MODEL;
    u16* Vtw  = Kw   + (size_t)MTOT * D_MODEL;            // [b,h,d,s]
    u16* ctxb = Vtw  + (size_t)MTOT * D_MODEL;            // [4096][1024]

    cast_kernel<<<(MTOT * D_MODEL / 8 + 255) / 256, 256, 0, stream>>>(x, xb, MTOT * D_MODEL / 8);
    cast_qkv_kernel<<<(3 * D_MODEL * D_MODEL / 8 + 255) / 256, 256, 0, stream>>>(Wq, Wk, Wv, wqkv);
    cast_kernel<<<(D_MODEL * D_MODEL / 8 + 255) / 256, 256, 0, stream>>>(Wo, wob, D_MODEL * D_MODEL / 8);

    dim3 gq(3 * D_MODEL / 128, MTOT / 128);
    gemm_qkv_kernel<<<gq, 256, 0, stream>>>(xb, wqkv, Qw, Kw, Vtw);

    dim3 ga(SEQ / 64, BATCH * NUM_HEADS);
    attn_kernel<<<ga, 256, 0, stream>>>(Qw, Kw, Vtw, ctxb);

    dim3 go(D_MODEL / 128, MTOT / 128);
    gemm_out_kernel<<<go, 256, 0, stream>>>(ctxb, wob, bo, out);
}

// Round 4
// 151.576 us; speedup vs baseline: 19.0473x; 1.3918x over previous
//
#include <hip/hip_runtime.h>

#define D_MODEL 1024
#define NUM_HEADS 16
#define HEAD_DIM 64
#define BATCH 2
#define SEQ 2048
#define MTOT (BATCH * SEQ)   // 4096

typedef __attribute__((ext_vector_type(8))) short bf16x8;   // 8 bf16 in 4 VGPRs
typedef __attribute__((ext_vector_type(4))) short s16x4;
typedef __attribute__((ext_vector_type(4))) float f32x4;
typedef unsigned short u16;

__device__ __forceinline__ u16 f2bf(float f) {
    unsigned u = __float_as_uint(f);
    return (u16)((u + 0x7FFFu + ((u >> 16) & 1u)) >> 16);   // RNE, finite data
}

__device__ __forceinline__ unsigned cvt_pk_bf16(float lo, float hi) {
    unsigned r;
    asm volatile("v_cvt_pk_bf16_f32 %0, %1, %2" : "=v"(r) : "v"(lo), "v"(hi));
    return r;   // low16 = bf16(lo), high16 = bf16(hi)
}

#define GLOAD16(gp, lp) __builtin_amdgcn_global_load_lds(                      \
    (const __attribute__((address_space(1))) void*)(gp),                       \
    (__attribute__((address_space(3))) void*)(lp), 16, 0, 0)

// ---------------------------------------------------------------------------
// fp32 -> bf16 casts
// ---------------------------------------------------------------------------
__global__ __launch_bounds__(256)
void cast_kernel(const float* __restrict__ src, u16* __restrict__ dst, int n8)
{
    int i = blockIdx.x * 256 + threadIdx.x;
    if (i >= n8) return;
    const float4* s = reinterpret_cast<const float4*>(src) + (size_t)i * 2;
    float4 a = s[0], b = s[1];
    u16 tmp[8] = {f2bf(a.x), f2bf(a.y), f2bf(a.z), f2bf(a.w),
                  f2bf(b.x), f2bf(b.y), f2bf(b.z), f2bf(b.w)};
    *reinterpret_cast<int4*>(dst + (size_t)i * 8) = *reinterpret_cast<int4*>(tmp);
}

__global__ __launch_bounds__(256)
void cast_qkv_kernel(const float* __restrict__ Wq, const float* __restrict__ Wk,
                     const float* __restrict__ Wv, u16* __restrict__ dst)
{
    int i = blockIdx.x * 256 + threadIdx.x;
    int z = i >> 17;
    int j = i & 0x1FFFF;
    const float* src = (z == 0) ? Wq : (z == 1) ? Wk : Wv;
    const float4* s = reinterpret_cast<const float4*>(src) + (size_t)j * 2;
    float4 a = s[0], b = s[1];
    u16 tmp[8] = {f2bf(a.x), f2bf(a.y), f2bf(a.z), f2bf(a.w),
                  f2bf(b.x), f2bf(b.y), f2bf(b.z), f2bf(b.w)};
    *reinterpret_cast<int4*>(dst + (size_t)i * 8) = *reinterpret_cast<int4*>(tmp);
}

// ---------------------------------------------------------------------------
// QKV GEMM: xb[4096][1024] @ Wqkv[3072][1024]^T, bf16 MFMA, m97 structure.
// Scatters Q (pre-scaled by 1/8), K to [b,h,s,d]; V transposed to [b,h,d,s].
// ---------------------------------------------------------------------------
__global__ __launch_bounds__(256)
void gemm_qkv_kernel(const u16* __restrict__ A, const u16* __restrict__ B,
                     u16* __restrict__ Qo, u16* __restrict__ Ko, u16* __restrict__ Vt)
{
    __shared__ u16 Al[128 * 64];
    __shared__ u16 Bl[128 * 64];

    const int tid = threadIdx.x;
    const int l = tid & 63;
    const int w = tid >> 6;
    const int wm = w >> 1, wn = w & 1;
    const int lr = l & 15, lg = l >> 4;
    const int m0 = blockIdx.y * 128;
    const int n0 = blockIdx.x * 128;

    const int srow = tid >> 3;
    const int scol = (tid & 7) * 8;

    f32x4 acc[4][4];
    #pragma unroll
    for (int i = 0; i < 4; ++i)
        #pragma unroll
        for (int j = 0; j < 4; ++j) acc[i][j] = (f32x4){0.f, 0.f, 0.f, 0.f};

    for (int k0 = 0; k0 < D_MODEL; k0 += 64) {
        __syncthreads();
        #pragma unroll
        for (int i = 0; i < 4; ++i) {
            const u16* ga = A + (size_t)(m0 + i * 32 + srow) * D_MODEL + k0 + scol;
            const u16* gb = B + (size_t)(n0 + i * 32 + srow) * D_MODEL + k0 + scol;
            GLOAD16(ga, Al + i * 2048 + w * 512);
            GLOAD16(gb, Bl + i * 2048 + w * 512);
        }
        __syncthreads();
        #pragma unroll
        for (int kc = 0; kc < 2; ++kc) {
            bf16x8 af[4], bfr[4];
            #pragma unroll
            for (int i = 0; i < 4; ++i)
                af[i] = *reinterpret_cast<const bf16x8*>(
                    &Al[(wm * 64 + i * 16 + lr) * 64 + kc * 32 + lg * 8]);
            #pragma unroll
            for (int j = 0; j < 4; ++j)
                bfr[j] = *reinterpret_cast<const bf16x8*>(
                    &Bl[(wn * 64 + j * 16 + lr) * 64 + kc * 32 + lg * 8]);
            #pragma unroll
            for (int i = 0; i < 4; ++i)
                #pragma unroll
                for (int j = 0; j < 4; ++j)
                    acc[i][j] = __builtin_amdgcn_mfma_f32_16x16x32_bf16(
                        af[i], bfr[j], acc[i][j], 0, 0, 0);
        }
    }

    const int z = (n0 >> 10);           // 0=Q 1=K 2=V (uniform per block)
    #pragma unroll
    for (int i = 0; i < 4; ++i) {
        #pragma unroll
        for (int r = 0; r < 4; ++r) {
            const int m = m0 + wm * 64 + i * 16 + lg * 4 + r;
            const int bb = m >> 11, s = m & (SEQ - 1);
            #pragma unroll
            for (int j = 0; j < 4; ++j) {
                const int c = n0 + wn * 64 + j * 16 + lr;
                const int cc = c & 1023, h = cc >> 6, d = cc & 63;
                if (z == 0)
                    Qo[((size_t)(bb * NUM_HEADS + h) * SEQ + s) * 64 + d] =
                        f2bf(acc[i][j][r] * 0.125f);     // fold 1/sqrt(64)
                else if (z == 1)
                    Ko[((size_t)(bb * NUM_HEADS + h) * SEQ + s) * 64 + d] =
                        f2bf(acc[i][j][r]);
                else
                    Vt[((size_t)(bb * NUM_HEADS + h) * 64 + d) * SEQ + s] =
                        f2bf(acc[i][j][r]);
            }
        }
    }
}

// ---------------------------------------------------------------------------
// Output GEMM: ctx[4096][1024] @ Wo[1024][1024]^T + bo, fp32 out.
// ---------------------------------------------------------------------------
__global__ __launch_bounds__(256)
void gemm_out_kernel(const u16* __restrict__ A, const u16* __restrict__ B,
                     const float* __restrict__ bias, float* __restrict__ out)
{
    __shared__ u16 Al[128 * 64];
    __shared__ u16 Bl[128 * 64];

    const int tid = threadIdx.x;
    const int l = tid & 63;
    const int w = tid >> 6;
    const int wm = w >> 1, wn = w & 1;
    const int lr = l & 15, lg = l >> 4;
    const int m0 = blockIdx.y * 128;
    const int n0 = blockIdx.x * 128;

    const int srow = tid >> 3;
    const int scol = (tid & 7) * 8;

    f32x4 acc[4][4];
    #pragma unroll
    for (int i = 0; i < 4; ++i)
        #pragma unroll
        for (int j = 0; j < 4; ++j) acc[i][j] = (f32x4){0.f, 0.f, 0.f, 0.f};

    for (int k0 = 0; k0 < D_MODEL; k0 += 64) {
        __syncthreads();
        #pragma unroll
        for (int i = 0; i < 4; ++i) {
            const u16* ga = A + (size_t)(m0 + i * 32 + srow) * D_MODEL + k0 + scol;
            const u16* gb = B + (size_t)(n0 + i * 32 + srow) * D_MODEL + k0 + scol;
            GLOAD16(ga, Al + i * 2048 + w * 512);
            GLOAD16(gb, Bl + i * 2048 + w * 512);
        }
        __syncthreads();
        #pragma unroll
        for (int kc = 0; kc < 2; ++kc) {
            bf16x8 af[4], bfr[4];
            #pragma unroll
            for (int i = 0; i < 4; ++i)
                af[i] = *reinterpret_cast<const bf16x8*>(
                    &Al[(wm * 64 + i * 16 + lr) * 64 + kc * 32 + lg * 8]);
            #pragma unroll
            for (int j = 0; j < 4; ++j)
                bfr[j] = *reinterpret_cast<const bf16x8*>(
                    &Bl[(wn * 64 + j * 16 + lr) * 64 + kc * 32 + lg * 8]);
            #pragma unroll
            for (int i = 0; i < 4; ++i)
                #pragma unroll
                for (int j = 0; j < 4; ++j)
                    acc[i][j] = __builtin_amdgcn_mfma_f32_16x16x32_bf16(
                        af[i], bfr[j], acc[i][j], 0, 0, 0);
        }
    }

    #pragma unroll
    for (int i = 0; i < 4; ++i) {
        #pragma unroll
        for (int r = 0; r < 4; ++r) {
            const int m = m0 + wm * 64 + i * 16 + lg * 4 + r;
            #pragma unroll
            for (int j = 0; j < 4; ++j) {
                const int c = n0 + wn * 64 + j * 16 + lr;
                out[(size_t)m * D_MODEL + c] = acc[i][j][r] + bias[c];
            }
        }
    }
}

// ---------------------------------------------------------------------------
// MFMA causal flash attention, swapped-operand form.
// 4 waves/block, 16 queries/wave, KVBLK=64. Per lane: query = lane&15.
// S^T = mfma(K, Q); O^T = mfma(V^T-gathered, P^T). No S transpose, no
// rescale shfls. K/V LDS XOR-swizzled (byte ^= (row&7)<<4). q-tile pairs
// {i, 31-i} for perfect load balance (33 tiles/block).
// ---------------------------------------------------------------------------
__global__ __launch_bounds__(256)
void attn_kernel(const u16* __restrict__ Q, const u16* __restrict__ K,
                 const u16* __restrict__ Vt, u16* __restrict__ ctx)
{
    __shared__ char KsB[64 * 128];   // [key][d], swizzled
    __shared__ char VsB[64 * 128];   // [d][key], swizzled

    const int tid = threadIdx.x;
    const int l = tid & 63;
    const int w = tid >> 6;
    const int lr = l & 15;
    const int lg = l >> 4;
    const int bh = blockIdx.y;
    const size_t hbase = (size_t)bh * SEQ * 64;
    const int b = bh >> 4, h = bh & (NUM_HEADS - 1);

    // staging: thread -> row tid>>2, two 16B slots at byte cols (tid&3)*32 +{0,16}
    const int srow = tid >> 2;
    const int scb = (tid & 3) * 32;
    const int sswz = (srow & 7) << 4;
    char* kd0 = KsB + srow * 128 + (scb ^ sswz);
    char* kd1 = KsB + srow * 128 + ((scb + 16) ^ sswz);
    char* vd0 = VsB + srow * 128 + (scb ^ sswz);
    char* vd1 = VsB + srow * 128 + ((scb + 16) ^ sswz);
    const int rswz = (lr & 7) << 4;

    for (int qsel = 0; qsel < 2; ++qsel) {
        const int qtb = qsel ? (31 - blockIdx.x) : blockIdx.x;
        const int q0 = qtb * 64;
        const int qrow = q0 + w * 16 + lr;

        bf16x8 qf0, qf1;
        {
            const u16* qp = Q + hbase + (size_t)qrow * 64 + lg * 8;
            qf0 = *reinterpret_cast<const bf16x8*>(qp);
            qf1 = *reinterpret_cast<const bf16x8*>(qp + 32);
        }

        f32x4 oacc[4];
        #pragma unroll
        for (int nb = 0; nb < 4; ++nb) oacc[nb] = (f32x4){0.f, 0.f, 0.f, 0.f};
        float mrun = -3.0e38f, lsum = 0.f;

        // preload tile 0 into regs (T14: global->reg early, reg->LDS late)
        int4 ka, kb2, va2, vb2;
        {
            const u16* kg = K + hbase + (size_t)srow * 64 + (tid & 3) * 16;
            const u16* vg = Vt + hbase + (size_t)srow * SEQ + (tid & 3) * 16;
            ka  = *reinterpret_cast<const int4*>(kg);
            kb2 = *reinterpret_cast<const int4*>(kg + 8);
            va2 = *reinterpret_cast<const int4*>(vg);
            vb2 = *reinterpret_cast<const int4*>(vg + 8);
        }

        for (int kt = 0; kt <= qtb; ++kt) {
            __syncthreads();                       // prior tile's LDS reads done
            *reinterpret_cast<int4*>(kd0) = ka;
            *reinterpret_cast<int4*>(kd1) = kb2;
            *reinterpret_cast<int4*>(vd0) = va2;
            *reinterpret_cast<int4*>(vd1) = vb2;
            __syncthreads();
            if (kt < qtb) {                        // issue next tile's loads now
                const u16* kg = K + hbase + (size_t)((kt + 1) * 64 + srow) * 64 + (tid & 3) * 16;
                const u16* vg = Vt + hbase + (size_t)srow * SEQ + (kt + 1) * 64 + (tid & 3) * 16;
                ka  = *reinterpret_cast<const int4*>(kg);
                kb2 = *reinterpret_cast<const int4*>(kg + 8);
                va2 = *reinterpret_cast<const int4*>(vg);
                vb2 = *reinterpret_cast<const int4*>(vg + 8);
            }

            // S^T = K . Q^T : lane holds keys kt*64 + 16m + 4lg + r for query lr
            f32x4 s[4];
            #pragma unroll
            for (int m = 0; m < 4; ++m) {
                s[m] = (f32x4){0.f, 0.f, 0.f, 0.f};
                const char* krow = KsB + (16 * m + lr) * 128;
                bf16x8 kf0 = *reinterpret_cast<const bf16x8*>(krow + ((lg * 16) ^ rswz));
                bf16x8 kf1 = *reinterpret_cast<const bf16x8*>(krow + ((64 + lg * 16) ^ rswz));
                s[m] = __builtin_amdgcn_mfma_f32_16x16x32_bf16(kf0, qf0, s[m], 0, 0, 0);
                s[m] = __builtin_amdgcn_mfma_f32_16x16x32_bf16(kf1, qf1, s[m], 0, 0, 0);
            }

            if (kt == qtb) {                       // diagonal tile: causal mask
                #pragma unroll
                for (int m = 0; m < 4; ++m)
                    #pragma unroll
                    for (int r = 0; r < 4; ++r)
                        if (16 * m + 4 * lg + r > 16 * w + lr) s[m][r] = -3.0e38f;
            }

            float pmax = s[0][0];
            #pragma unroll
            for (int m = 0; m < 4; ++m)
                #pragma unroll
                for (int r = 0; r < 4; ++r) pmax = fmaxf(pmax, s[m][r]);
            pmax = fmaxf(pmax, __shfl_xor(pmax, 16));
            pmax = fmaxf(pmax, __shfl_xor(pmax, 32));

            const float mnew = fmaxf(mrun, pmax);
            const float corr = __expf(mrun - mnew);
            mrun = mnew;
            lsum *= corr;
            #pragma unroll
            for (int nb = 0; nb < 4; ++nb) {
                oacc[nb][0] *= corr; oacc[nb][1] *= corr;
                oacc[nb][2] *= corr; oacc[nb][3] *= corr;
            }

            float p[4][4];
            float ps = 0.f;
            #pragma unroll
            for (int m = 0; m < 4; ++m)
                #pragma unroll
                for (int r = 0; r < 4; ++r) {
                    p[m][r] = __expf(s[m][r] - mnew);
                    ps += p[m][r];
                }
            ps += __shfl_xor(ps, 16);
            ps += __shfl_xor(ps, 32);
            lsum += ps;

            unsigned dw[4][2];
            #pragma unroll
            for (int m = 0; m < 4; ++m) {
                dw[m][0] = cvt_pk_bf16(p[m][0], p[m][1]);
                dw[m][1] = cvt_pk_bf16(p[m][2], p[m][3]);
            }

            // O^T += V^T . P^T with k-axis bijection K(c, 8lg+j):
            // A-frag gathers V cols {32c+4lg..+3, 32c+16+4lg..+3}; B-frag is
            // exactly this lane's own packed P dwords. Zero cross-lane traffic.
            #pragma unroll
            for (int c = 0; c < 2; ++c) {
                union { unsigned u[4]; bf16x8 v; } pb;
                pb.u[0] = dw[2 * c][0];     pb.u[1] = dw[2 * c][1];
                pb.u[2] = dw[2 * c + 1][0]; pb.u[3] = dw[2 * c + 1][1];
                #pragma unroll
                for (int nb = 0; nb < 4; ++nb) {
                    const char* vrow = VsB + (16 * nb + lr) * 128;
                    union { s16x4 h[2]; bf16x8 v; } vf;
                    vf.h[0] = *reinterpret_cast<const s16x4*>(vrow + ((c * 64 + lg * 8) ^ rswz));
                    vf.h[1] = *reinterpret_cast<const s16x4*>(vrow + ((c * 64 + 32 + lg * 8) ^ rswz));
                    oacc[nb] = __builtin_amdgcn_mfma_f32_16x16x32_bf16(
                        vf.v, pb.v, oacc[nb], 0, 0, 0);
                }
            }
        }

        const float inv = 1.0f / lsum;
        u16* op = ctx + ((size_t)(b * SEQ) + qrow) * D_MODEL + h * 64 + 4 * lg;
        #pragma unroll
        for (int nb = 0; nb < 4; ++nb) {
            u16 t4[4];
            #pragma unroll
            for (int r = 0; r < 4; ++r) t4[r] = f2bf(oacc[nb][r] * inv);
            *reinterpret_cast<unsigned long long*>(op + 16 * nb) =
                *reinterpret_cast<unsigned long long*>(t4);
        }
    }
}

// ---------------------------------------------------------------------------

extern "C" void kernel_launch(void* const* d_in, const int* in_sizes, int n_in,
                              void* d_out, int out_size, void* d_ws, size_t ws_size,
                              hipStream_t stream)
{
    const float* x  = (const float*)d_in[0];
    const float* Wq = (const float*)d_in[1];
    const float* Wk = (const float*)d_in[2];
    const float* Wv = (const float*)d_in[3];
    const float* Wo = (const float*)d_in[4];
    const float* bo = (const float*)d_in[5];
    float* out = (float*)d_out;

    u16* xb   = (u16*)d_ws;                               // 4096*1024
    u16* wqkv = xb   + (size_t)MTOT * D_MODEL;            // 3072*1024
    u16* wob  = wqkv + (size_t)3 * D_MODEL * D_MODEL;     // 1024*1024
    u16* Qw   = wob  + (size_t)D_MODEL * D_MODEL;         // [b,h,s,d] (pre-scaled)
    u16* Kw   = Qw   + (size_t)MTOT * D_MODEL;            // [b,h,s,d]
    u16* Vtw  = Kw   + (size_t)MTOT * D_MODEL;            // [b,h,d,s]
    u16* ctxb = Vtw  + (size_t)MTOT * D_MODEL;            // [4096][1024]

    cast_kernel<<<(MTOT * D_MODEL / 8 + 255) / 256, 256, 0, stream>>>(x, xb, MTOT * D_MODEL / 8);
    cast_qkv_kernel<<<(3 * D_MODEL * D_MODEL / 8 + 255) / 256, 256, 0, stream>>>(Wq, Wk, Wv, wqkv);
    cast_kernel<<<(D_MODEL * D_MODEL / 8 + 255) / 256, 256, 0, stream>>>(Wo, wob, D_MODEL * D_MODEL / 8);

    dim3 gq(3 * D_MODEL / 128, MTOT / 128);
    gemm_qkv_kernel<<<gq, 256, 0, stream>>>(xb, wqkv, Qw, Kw, Vtw);

    dim3 ga(16, BATCH * NUM_HEADS);      // q-tile pairs {i, 31-i}
    attn_kernel<<<ga, 256, 0, stream>>>(Qw, Kw, Vtw, ctxb);

    dim3 go(D_MODEL / 128, MTOT / 128);
    gemm_out_kernel<<<go, 256, 0, stream>>>(ctxb, wob, bo, out);
}

// Round 5
// 127.366 us; speedup vs baseline: 22.6679x; 1.1901x over previous
//
#include <hip/hip_runtime.h>

#define D_MODEL 1024
#define NUM_HEADS 16
#define HEAD_DIM 64
#define BATCH 2
#define SEQ 2048
#define MTOT (BATCH * SEQ)   // 4096

typedef __attribute__((ext_vector_type(8))) short bf16x8;   // 8 bf16 in 4 VGPRs
typedef __attribute__((ext_vector_type(4))) short s16x4;
typedef __attribute__((ext_vector_type(4))) float f32x4;
typedef unsigned short u16;
typedef unsigned long long u64;

__device__ __forceinline__ u16 f2bf(float f) {
    unsigned u = __float_as_uint(f);
    return (u16)((u + 0x7FFFu + ((u >> 16) & 1u)) >> 16);   // RNE, finite data
}

__device__ __forceinline__ unsigned cvt_pk_bf16(float lo, float hi) {
    unsigned r;
    asm volatile("v_cvt_pk_bf16_f32 %0, %1, %2" : "=v"(r) : "v"(lo), "v"(hi));
    return r;
}

#define GLOAD16(gp, lp) __builtin_amdgcn_global_load_lds(                      \
    (const __attribute__((address_space(1))) void*)(gp),                       \
    (__attribute__((address_space(3))) void*)(lp), 16, 0, 0)

// ---------------------------------------------------------------------------
// One merged fp32 -> bf16 cast: x | Wqkv | Wo into contiguous ws region.
// ---------------------------------------------------------------------------
__global__ __launch_bounds__(256)
void cast_all_kernel(const float* __restrict__ x,  const float* __restrict__ Wq,
                     const float* __restrict__ Wk, const float* __restrict__ Wv,
                     const float* __restrict__ Wo, u16* __restrict__ dst)
{
    const int i = blockIdx.x * 256 + threadIdx.x;   // 1048576 groups of 8
    const float* src;
    int j;
    if (i < 524288) { src = x; j = i; }
    else if (i < 917504) {
        const int k = i - 524288;
        const int z = k >> 17;
        src = (z == 0) ? Wq : (z == 1) ? Wk : Wv;
        j = k & 0x1FFFF;
    } else { src = Wo; j = i - 917504; }
    const float4* s = reinterpret_cast<const float4*>(src) + (size_t)j * 2;
    float4 a = s[0], b = s[1];
    u16 tmp[8] = {f2bf(a.x), f2bf(a.y), f2bf(a.z), f2bf(a.w),
                  f2bf(b.x), f2bf(b.y), f2bf(b.z), f2bf(b.w)};
    *reinterpret_cast<int4*>(dst + (size_t)i * 8) = *reinterpret_cast<int4*>(tmp);
}

// ---------------------------------------------------------------------------
// QKV GEMM: xb[4096][1024] @ Wqkv[3072][1024]^T, bf16 MFMA, m97 structure
// + T2 swizzle (pre-swizzled gload source, XOR on fragment reads).
// Scatters Q (pre-scaled 1/8), K to [b,h,s,d]; V transposed to [b,h,d,s].
// ---------------------------------------------------------------------------
__global__ __launch_bounds__(256)
void gemm_qkv_kernel(const u16* __restrict__ A, const u16* __restrict__ B,
                     u16* __restrict__ Qo, u16* __restrict__ Ko, u16* __restrict__ Vt)
{
    __shared__ u16 Al[128 * 64];
    __shared__ u16 Bl[128 * 64];

    const int tid = threadIdx.x;
    const int l = tid & 63;
    const int w = tid >> 6;
    const int wm = w >> 1, wn = w & 1;
    const int lr = l & 15, lg = l >> 4;
    const int m0 = blockIdx.y * 128;
    const int n0 = blockIdx.x * 128;

    const int srow = tid >> 3;
    const int scol = ((tid & 7) ^ (srow & 7)) * 8;   // inverse-swizzled source col
    const int sxa = (lr & 7) * 8;                    // read-side XOR (elements)

    f32x4 acc[4][4];
    #pragma unroll
    for (int i = 0; i < 4; ++i)
        #pragma unroll
        for (int j = 0; j < 4; ++j) acc[i][j] = (f32x4){0.f, 0.f, 0.f, 0.f};

    for (int k0 = 0; k0 < D_MODEL; k0 += 64) {
        __syncthreads();
        #pragma unroll
        for (int i = 0; i < 4; ++i) {
            const u16* ga = A + (size_t)(m0 + i * 32 + srow) * D_MODEL + k0 + scol;
            const u16* gb = B + (size_t)(n0 + i * 32 + srow) * D_MODEL + k0 + scol;
            GLOAD16(ga, Al + i * 2048 + w * 512);
            GLOAD16(gb, Bl + i * 2048 + w * 512);
        }
        __syncthreads();
        #pragma unroll
        for (int kc = 0; kc < 2; ++kc) {
            bf16x8 af[4], bfr[4];
            #pragma unroll
            for (int i = 0; i < 4; ++i)
                af[i] = *reinterpret_cast<const bf16x8*>(
                    &Al[(wm * 64 + i * 16 + lr) * 64 + ((kc * 32 + lg * 8) ^ sxa)]);
            #pragma unroll
            for (int j = 0; j < 4; ++j)
                bfr[j] = *reinterpret_cast<const bf16x8*>(
                    &Bl[(wn * 64 + j * 16 + lr) * 64 + ((kc * 32 + lg * 8) ^ sxa)]);
            #pragma unroll
            for (int i = 0; i < 4; ++i)
                #pragma unroll
                for (int j = 0; j < 4; ++j)
                    acc[i][j] = __builtin_amdgcn_mfma_f32_16x16x32_bf16(
                        af[i], bfr[j], acc[i][j], 0, 0, 0);
        }
    }

    const int z = (n0 >> 10);           // 0=Q 1=K 2=V (uniform per block)
    if (z < 2) {
        #pragma unroll
        for (int i = 0; i < 4; ++i) {
            #pragma unroll
            for (int r = 0; r < 4; ++r) {
                const int m = m0 + wm * 64 + i * 16 + lg * 4 + r;
                const int bb = m >> 11, s = m & (SEQ - 1);
                #pragma unroll
                for (int j = 0; j < 4; ++j) {
                    const int c = n0 + wn * 64 + j * 16 + lr;
                    const int cc = c & 1023, h = cc >> 6, d = cc & 63;
                    const size_t idx = ((size_t)(bb * NUM_HEADS + h) * SEQ + s) * 64 + d;
                    if (z == 0) Qo[idx] = f2bf(acc[i][j][r] * 0.125f);
                    else        Ko[idx] = f2bf(acc[i][j][r]);
                }
            }
        }
    } else {
        #pragma unroll
        for (int i = 0; i < 4; ++i) {
            const int mbase = m0 + wm * 64 + i * 16 + lg * 4;   // 4 consecutive s
            const int bb = mbase >> 11, s = mbase & (SEQ - 1);
            #pragma unroll
            for (int j = 0; j < 4; ++j) {
                const int c = n0 + wn * 64 + j * 16 + lr;
                const int cc = c & 1023, h = cc >> 6, d = cc & 63;
                u16 t4[4];
                #pragma unroll
                for (int r = 0; r < 4; ++r) t4[r] = f2bf(acc[i][j][r]);
                *reinterpret_cast<u64*>(
                    &Vt[((size_t)(bb * NUM_HEADS + h) * 64 + d) * SEQ + s]) =
                    *reinterpret_cast<u64*>(t4);
            }
        }
    }
}

// ---------------------------------------------------------------------------
// Output GEMM: ctx[4096][1024] @ Wo[1024][1024]^T + bo, fp32 out. +T2 swizzle.
// ---------------------------------------------------------------------------
__global__ __launch_bounds__(256)
void gemm_out_kernel(const u16* __restrict__ A, const u16* __restrict__ B,
                     const float* __restrict__ bias, float* __restrict__ out)
{
    __shared__ u16 Al[128 * 64];
    __shared__ u16 Bl[128 * 64];

    const int tid = threadIdx.x;
    const int l = tid & 63;
    const int w = tid >> 6;
    const int wm = w >> 1, wn = w & 1;
    const int lr = l & 15, lg = l >> 4;
    const int m0 = blockIdx.y * 128;
    const int n0 = blockIdx.x * 128;

    const int srow = tid >> 3;
    const int scol = ((tid & 7) ^ (srow & 7)) * 8;
    const int sxa = (lr & 7) * 8;

    f32x4 acc[4][4];
    #pragma unroll
    for (int i = 0; i < 4; ++i)
        #pragma unroll
        for (int j = 0; j < 4; ++j) acc[i][j] = (f32x4){0.f, 0.f, 0.f, 0.f};

    for (int k0 = 0; k0 < D_MODEL; k0 += 64) {
        __syncthreads();
        #pragma unroll
        for (int i = 0; i < 4; ++i) {
            const u16* ga = A + (size_t)(m0 + i * 32 + srow) * D_MODEL + k0 + scol;
            const u16* gb = B + (size_t)(n0 + i * 32 + srow) * D_MODEL + k0 + scol;
            GLOAD16(ga, Al + i * 2048 + w * 512);
            GLOAD16(gb, Bl + i * 2048 + w * 512);
        }
        __syncthreads();
        #pragma unroll
        for (int kc = 0; kc < 2; ++kc) {
            bf16x8 af[4], bfr[4];
            #pragma unroll
            for (int i = 0; i < 4; ++i)
                af[i] = *reinterpret_cast<const bf16x8*>(
                    &Al[(wm * 64 + i * 16 + lr) * 64 + ((kc * 32 + lg * 8) ^ sxa)]);
            #pragma unroll
            for (int j = 0; j < 4; ++j)
                bfr[j] = *reinterpret_cast<const bf16x8*>(
                    &Bl[(wn * 64 + j * 16 + lr) * 64 + ((kc * 32 + lg * 8) ^ sxa)]);
            #pragma unroll
            for (int i = 0; i < 4; ++i)
                #pragma unroll
                for (int j = 0; j < 4; ++j)
                    acc[i][j] = __builtin_amdgcn_mfma_f32_16x16x32_bf16(
                        af[i], bfr[j], acc[i][j], 0, 0, 0);
        }
    }

    #pragma unroll
    for (int i = 0; i < 4; ++i) {
        #pragma unroll
        for (int r = 0; r < 4; ++r) {
            const int m = m0 + wm * 64 + i * 16 + lg * 4 + r;
            #pragma unroll
            for (int j = 0; j < 4; ++j) {
                const int c = n0 + wn * 64 + j * 16 + lr;
                out[(size_t)m * D_MODEL + c] = acc[i][j][r] + bias[c];
            }
        }
    }
}

// ---------------------------------------------------------------------------
// MFMA causal flash attention, swapped-operand form + pipelined staging.
// 4 waves/block, 16 queries/wave. KVBLK=128 staged per barrier-pair via
// global_load_lds into double-buffered LDS (2x32KB), counted vmcnt(8),
// raw s_barrier (no drain). Two 64-key compute halves per stage; diagonal
// half skipped when fully masked. T13 defer-max, T5 setprio.
// ---------------------------------------------------------------------------
__global__ __launch_bounds__(256)
void attn_kernel(const u16* __restrict__ Q, const u16* __restrict__ K,
                 const u16* __restrict__ Vt, u16* __restrict__ ctx)
{
    __shared__ char LdsB[65536];   // buf b: K 16KB @ b*32768, V 16KB @ +16384

    const int tid = threadIdx.x;
    const int l = tid & 63;
    const int w = tid >> 6;
    const int lr = l & 15;
    const int lg = l >> 4;
    const int bh = blockIdx.y;
    const size_t hbase = (size_t)bh * SEQ * 64;
    const int b = bh >> 4, h = bh & (NUM_HEADS - 1);
    const u16* __restrict__ Kh = K + hbase;
    const u16* __restrict__ Vh = Vt + hbase;

    // staging geometry (per thread): 4 K-loads + 4 V-loads, linear LDS dest,
    // inverse-swizzled global source (rule #21).
    const int krow_t = tid >> 3;                              // 0..31
    const int kcol   = ((tid & 7) ^ ((tid >> 3) & 7)) * 8;    // elements
    const int vrow_t = tid >> 4;                              // 0..15
    const int vcol   = ((tid & 15) ^ ((tid >> 4) & 7)) * 8;   // elements
    const int ldst   = tid * 16;                              // bytes
    const int rswz   = (lr & 7) << 4;                         // read-side XOR (bytes)

    for (int qsel = 0; qsel < 2; ++qsel) {
        const int qtb = qsel ? (31 - blockIdx.x) : blockIdx.x;
        const int q0 = qtb * 64;
        const int qrow = q0 + w * 16 + lr;

        bf16x8 qf0, qf1;
        {
            const u16* qp = Q + hbase + (size_t)qrow * 64 + lg * 8;
            qf0 = *reinterpret_cast<const bf16x8*>(qp);
            qf1 = *reinterpret_cast<const bf16x8*>(qp + 32);
        }
        // force Q-load retirement now so later counted vmcnt math is exact
        asm volatile("" :: "v"((int)qf0[0]), "v"((int)qf1[0]));

        f32x4 oacc[4];
        #pragma unroll
        for (int nb = 0; nb < 4; ++nb) oacc[nb] = (f32x4){0.f, 0.f, 0.f, 0.f};
        float mrun = -3.0e38f, lsum = 0.f;

        const int nstage = (qtb + 2) >> 1;    // ceil((qtb+1)/2)

        // prologue: stage 0 -> buf 0 (8 loads)
        {
            char* kb_l = LdsB;
            char* vb_l = LdsB + 16384;
            #pragma unroll
            for (int i = 0; i < 4; ++i) {
                GLOAD16(Kh + (size_t)(i * 32 + krow_t) * 64 + kcol, kb_l + i * 4096 + ldst);
                GLOAD16(Vh + (size_t)(i * 16 + vrow_t) * SEQ + vcol, vb_l + i * 4096 + ldst);
            }
        }

        for (int it = 0; it < nstage; ++it) {
            const int buf = it & 1;
            const bool pf = (it + 1 < nstage);
            if (pf) {                          // stage it+1 -> other buf
                const int kb = (it + 1) * 128;
                char* kb_l = LdsB + ((buf ^ 1) << 15);
                char* vb_l = kb_l + 16384;
                #pragma unroll
                for (int i = 0; i < 4; ++i) {
                    GLOAD16(Kh + (size_t)(kb + i * 32 + krow_t) * 64 + kcol,
                            kb_l + i * 4096 + ldst);
                    GLOAD16(Vh + (size_t)(i * 16 + vrow_t) * SEQ + kb + vcol,
                            vb_l + i * 4096 + ldst);
                }
                asm volatile("s_waitcnt vmcnt(8)" ::: "memory");
            } else {
                asm volatile("s_waitcnt vmcnt(0)" ::: "memory");
            }
            __builtin_amdgcn_s_barrier();      // stage `it` visible to all waves

            const char* kbuf = LdsB + (buf << 15);
            const char* vbuf = kbuf + 16384;

            for (int hh = 0; hh < 2; ++hh) {
                const int j64 = 2 * it + hh;
                if (j64 > qtb) break;

                // S^T = K . Q^T : lane holds keys j64*64 + 16m + 4lg + r, query lr
                f32x4 s[4];
                __builtin_amdgcn_s_setprio(1);
                #pragma unroll
                for (int m = 0; m < 4; ++m) {
                    s[m] = (f32x4){0.f, 0.f, 0.f, 0.f};
                    const char* krow = kbuf + (hh * 64 + 16 * m + lr) * 128;
                    bf16x8 kf0 = *reinterpret_cast<const bf16x8*>(krow + ((lg * 16) ^ rswz));
                    bf16x8 kf1 = *reinterpret_cast<const bf16x8*>(krow + ((64 + lg * 16) ^ rswz));
                    s[m] = __builtin_amdgcn_mfma_f32_16x16x32_bf16(kf0, qf0, s[m], 0, 0, 0);
                    s[m] = __builtin_amdgcn_mfma_f32_16x16x32_bf16(kf1, qf1, s[m], 0, 0, 0);
                }
                __builtin_amdgcn_s_setprio(0);

                if (j64 == qtb) {              // diagonal: causal mask
                    #pragma unroll
                    for (int m = 0; m < 4; ++m)
                        #pragma unroll
                        for (int r = 0; r < 4; ++r)
                            if (16 * m + 4 * lg + r > 16 * w + lr) s[m][r] = -3.0e38f;
                }

                float pmax = s[0][0];
                #pragma unroll
                for (int m = 0; m < 4; ++m)
                    #pragma unroll
                    for (int r = 0; r < 4; ++r) pmax = fmaxf(pmax, s[m][r]);
                pmax = fmaxf(pmax, __shfl_xor(pmax, 16));
                pmax = fmaxf(pmax, __shfl_xor(pmax, 32));

                if (!__all(pmax - mrun <= 8.0f)) {       // T13 defer-max
                    const float mnew = fmaxf(mrun, pmax);
                    const float corr = __expf(mrun - mnew);
                    lsum *= corr;
                    #pragma unroll
                    for (int nb = 0; nb < 4; ++nb) {
                        oacc[nb][0] *= corr; oacc[nb][1] *= corr;
                        oacc[nb][2] *= corr; oacc[nb][3] *= corr;
                    }
                    mrun = mnew;
                }

                float p[4][4];
                float ps = 0.f;
                #pragma unroll
                for (int m = 0; m < 4; ++m)
                    #pragma unroll
                    for (int r = 0; r < 4; ++r) {
                        p[m][r] = __expf(s[m][r] - mrun);
                        ps += p[m][r];
                    }
                ps += __shfl_xor(ps, 16);
                ps += __shfl_xor(ps, 32);
                lsum += ps;

                unsigned dw[4][2];
                #pragma unroll
                for (int m = 0; m < 4; ++m) {
                    dw[m][0] = cvt_pk_bf16(p[m][0], p[m][1]);
                    dw[m][1] = cvt_pk_bf16(p[m][2], p[m][3]);
                }

                // O^T += V^T . P^T (k-axis bijection; lane-local P)
                __builtin_amdgcn_s_setprio(1);
                #pragma unroll
                for (int c = 0; c < 2; ++c) {
                    union { unsigned u[4]; bf16x8 v; } pb;
                    pb.u[0] = dw[2 * c][0];     pb.u[1] = dw[2 * c][1];
                    pb.u[2] = dw[2 * c + 1][0]; pb.u[3] = dw[2 * c + 1][1];
                    #pragma unroll
                    for (int nb = 0; nb < 4; ++nb) {
                        const char* vrow = vbuf + (16 * nb + lr) * 256 + hh * 128;
                        union { s16x4 hv[2]; bf16x8 v; } vf;
                        vf.hv[0] = *reinterpret_cast<const s16x4*>(
                            vrow + ((c * 64 + lg * 8) ^ rswz));
                        vf.hv[1] = *reinterpret_cast<const s16x4*>(
                            vrow + ((c * 64 + 32 + lg * 8) ^ rswz));
                        oacc[nb] = __builtin_amdgcn_mfma_f32_16x16x32_bf16(
                            vf.v, pb.v, oacc[nb], 0, 0, 0);
                    }
                }
                __builtin_amdgcn_s_setprio(0);
            }
            __builtin_amdgcn_s_barrier();      // all reads done before next DMA
        }

        const float inv = 1.0f / lsum;
        u16* op = ctx + ((size_t)(b * SEQ) + qrow) * D_MODEL + h * 64 + 4 * lg;
        #pragma unroll
        for (int nb = 0; nb < 4; ++nb) {
            u16 t4[4];
            #pragma unroll
            for (int r = 0; r < 4; ++r) t4[r] = f2bf(oacc[nb][r] * inv);
            *reinterpret_cast<u64*>(op + 16 * nb) = *reinterpret_cast<u64*>(t4);
        }
    }
}

// ---------------------------------------------------------------------------

extern "C" void kernel_launch(void* const* d_in, const int* in_sizes, int n_in,
                              void* d_out, int out_size, void* d_ws, size_t ws_size,
                              hipStream_t stream)
{
    const float* x  = (const float*)d_in[0];
    const float* Wq = (const float*)d_in[1];
    const float* Wk = (const float*)d_in[2];
    const float* Wv = (const float*)d_in[3];
    const float* Wo = (const float*)d_in[4];
    const float* bo = (const float*)d_in[5];
    float* out = (float*)d_out;

    u16* xb   = (u16*)d_ws;                               // 4096*1024
    u16* wqkv = xb   + (size_t)MTOT * D_MODEL;            // 3072*1024
    u16* wob  = wqkv + (size_t)3 * D_MODEL * D_MODEL;     // 1024*1024
    u16* Qw   = wob  + (size_t)D_MODEL * D_MODEL;         // [b,h,s,d] (pre-scaled)
    u16* Kw   = Qw   + (size_t)MTOT * D_MODEL;            // [b,h,s,d]
    u16* Vtw  = Kw   + (size_t)MTOT * D_MODEL;            // [b,h,d,s]
    u16* ctxb = Vtw  + (size_t)MTOT * D_MODEL;            // [4096][1024]

    cast_all_kernel<<<4096, 256, 0, stream>>>(x, Wq, Wk, Wv, Wo, xb);

    dim3 gq(3 * D_MODEL / 128, MTOT / 128);
    gemm_qkv_kernel<<<gq, 256, 0, stream>>>(xb, wqkv, Qw, Kw, Vtw);

    dim3 ga(16, BATCH * NUM_HEADS);      // q-tile pairs {i, 31-i}
    attn_kernel<<<ga, 256, 0, stream>>>(Qw, Kw, Vtw, ctxb);

    dim3 go(D_MODEL / 128, MTOT / 128);
    gemm_out_kernel<<<go, 256, 0, stream>>>(ctxb, wob, bo, out);
}